// Round 8
// baseline (208.712 us; speedup 1.0000x reference)
//
#include <hip/hip_runtime.h>

#define N_TOT 8192
#define BHALF 4096
#define D_DIM 512
#define BM 128
#define NTILE 64          // N_TOT / BM
#define NBLOCKS 2080      // NTILE*(NTILE+1)/2 upper-triangle tiles
#define BK2 32            // K per chunk
#define NCHUNK 16         // D_DIM / BK2

// Z is scaled by sqrt(2/ln2) at normalize time, so acc = (2/ln2)*cos and
// exp(2*cos) == exp2(acc) -> bare v_exp_f32 in the epilogue.
// The positive LOGIT (2*cos) is recovered as acc * ln2.
#define ZSCALE 1.69864368f      // sqrt(2/ln(2))
#define LN2F   0.69314718f

typedef float f32x4 __attribute__((ext_vector_type(4)));
typedef short s16x8 __attribute__((ext_vector_type(8)));  // 8 bf16 in 4 VGPRs

__device__ __forceinline__ unsigned short f2bf(float x) {
    union { float f; unsigned int u; } v; v.f = x;
    unsigned int lsb = (v.u >> 16) & 1u;
    unsigned int r = v.u + 0x7fffu + lsb;   // round-to-nearest-even
    return (unsigned short)(r >> 16);
}

__device__ __forceinline__ float fast_exp2(float x) {
#if __has_builtin(__builtin_amdgcn_exp2f)
    return __builtin_amdgcn_exp2f(x);
#else
    return exp2f(x);
#endif
}

// Kernel 1: row L2-normalize [zjs; zis] * ZSCALE -> bf16 Z.
// Blocks 0..31 zero rowsum.
__global__ __launch_bounds__(256) void normalize_kernel(
    const float* __restrict__ zis, const float* __restrict__ zjs,
    unsigned short* __restrict__ zb, float* __restrict__ rowsum)
{
    if (blockIdx.x < 32) rowsum[blockIdx.x * 256 + threadIdx.x] = 0.0f;
    int wave = threadIdx.x >> 6;
    int lane = threadIdx.x & 63;
    int row  = blockIdx.x * 4 + wave;
    const float* src = (row < BHALF) ? (zjs + (size_t)row * D_DIM)
                                     : (zis + (size_t)(row - BHALF) * D_DIM);
    const float4* src4 = (const float4*)src;
    float4 v0 = src4[lane * 2];
    float4 v1 = src4[lane * 2 + 1];
    float ss = v0.x*v0.x + v0.y*v0.y + v0.z*v0.z + v0.w*v0.w
             + v1.x*v1.x + v1.y*v1.y + v1.z*v1.z + v1.w*v1.w;
    #pragma unroll
    for (int off = 1; off < 64; off <<= 1) ss += __shfl_xor(ss, off);
    float scale = ZSCALE / fmaxf(sqrtf(ss), 1e-8f);

    float vals[8] = {v0.x, v0.y, v0.z, v0.w, v1.x, v1.y, v1.z, v1.w};
    unsigned short u[8];
    #pragma unroll
    for (int i = 0; i < 8; ++i) u[i] = f2bf(vals[i] * scale);
    uint4 o;
    o.x = u[0] | ((unsigned)u[1] << 16);
    o.y = u[2] | ((unsigned)u[3] << 16);
    o.z = u[4] | ((unsigned)u[5] << 16);
    o.w = u[6] | ((unsigned)u[7] << 16);
    ((uint4*)(zb + (size_t)row * D_DIM))[lane] = o;
}

// Kernel 2: upper-triangle 128x128 tiles of exp2(Zs.Zs^T), diag masked.
//
// ROUND 8 — NO LDS STAGING. R6/R7 PMC tally showed the LDS pipe ~63% busy
// (frag ds_reads 50k cyc/CU + staging writes 16k + epilogue shuffles 17k of
// 132k total) == the real bottleneck; setprio (R7) and deeper prefetch act
// on the wrong resources. After the XCD swizzle the per-XCD working set
// (~3.5 MB) is L2-resident (FETCH 19.9 MB), so per guide m169 ("don't stage
// what cache-fits") fragments are gathered DIRECTLY global->VGPR:
//   lane reads 16B at row (...+cq), k-slice quad*8  ->  per instruction the
//   wave touches 16 rows x 64B contiguous (all useful bytes, L1-cached, 2x
//   intra-block reuse); kc advances via the 13-bit immediate (kc*64B<=960).
// This deletes both per-chunk barriers, all staging, and the LDS swizzle;
// waves run fully desynchronized; LDS shrinks to 1 KB (epilogue sums only).
//
// XCD-CHUNKED SWIZZLE (round 6, verified: FETCH 72.8->19.9 MB): chunked
// bijective remap gives each XCD a contiguous 260-block range -> concurrent
// A/B-panel set ~3.5 MB fits the 4 MB per-XCD L2.
__global__ __launch_bounds__(256) void ntxent_tri_kernel(
    const unsigned short* __restrict__ zb, float* __restrict__ rowsum,
    float* __restrict__ pos_ws)
{
    __shared__ float sum_lds[256];   // rsum [0..127], csum [128..255]

    const int tid  = threadIdx.x;
    const int wave = tid >> 6;
    const int lane = tid & 63;
    const int cq   = lane & 15;
    const int quad = lane >> 4;
    const int wr   = wave >> 1;    // wave row 0..1
    const int wc   = wave & 1;     // wave col 0..1

    sum_lds[tid] = 0.0f;           // zero before any wave's epilogue atomics
    __syncthreads();

    // XCD-chunked bijective remap: wg i lands on XCD i%8 (round-robin HW
    // dispatch); give each XCD a contiguous 260-block range of the schedule.
    const int swzbid = (blockIdx.x & 7) * (NBLOCKS / 8) + (blockIdx.x >> 3);

    // swzbid -> (I,J), J-group-major (8 J-panels/group), I-major in group.
    int g = 0, rem = swzbid;
    while (rem >= 64 * g + 36) { rem -= 64 * g + 36; ++g; }
    int I, J;
    if (rem < 64 * g) { I = rem >> 3; J = 8 * g + (rem & 7); }
    else {
        rem -= 64 * g;
        int ii = 0;
        while (rem >= 8 - ii) { rem -= 8 - ii; ++ii; }
        I = 8 * g + ii;
        J = I + rem;
    }
    const int rowbase = I * BM;
    const int colbase = J * BM;
    const bool diagblk = (I == J);
    const bool posblk  = (J == I + NTILE / 2);   // contains (i, i+BHALF) pairs

    // Direct per-lane fragment pointers (16B-aligned). Same register layout
    // as the old LDS path: af[t] = 8 bf16 of row (wr*64+t*16+cq), k quad*8..+7.
    const unsigned short* pA[4];
    const unsigned short* pB[4];
    #pragma unroll
    for (int t = 0; t < 4; ++t) {
        pA[t] = zb + (size_t)(rowbase + wr * 64 + t * 16 + cq) * D_DIM + quad * 8;
        pB[t] = zb + (size_t)(colbase + wc * 64 + t * 16 + cq) * D_DIM + quad * 8;
    }

    f32x4 acc[4][4];
    #pragma unroll
    for (int a = 0; a < 4; ++a)
        #pragma unroll
        for (int b = 0; b < 4; ++b)
            acc[a][b] = (f32x4){0.f, 0.f, 0.f, 0.f};

    // K-loop: pure dataflow, no barriers. Compiler pipelines loads across
    // iterations up to its register-pressure target and inserts counted
    // vmcnt waits from the dataflow.
    #pragma unroll
    for (int kc = 0; kc < NCHUNK; ++kc) {
        s16x8 af[4], bf[4];
        #pragma unroll
        for (int t = 0; t < 4; ++t) {
            af[t] = *(const s16x8*)(pA[t] + kc * BK2);
            bf[t] = *(const s16x8*)(pB[t] + kc * BK2);
        }
        #pragma unroll
        for (int ar = 0; ar < 4; ++ar)
            #pragma unroll
            for (int bc = 0; bc < 4; ++bc)
                acc[ar][bc] = __builtin_amdgcn_mfma_f32_16x16x32_bf16(
                    af[ar], bf[bc], acc[ar][bc], 0, 0, 0);
    }

    // pos extraction BEFORE exp: gc == gr + BHALF  <=>  wc==wr, bc==ar, cq==quad*4+reg
    // acc = (2/ln2)*cos -> logit (2*cos) = acc * ln2. Plain store: the separate
    // finalize kernel launch is the synchronization point.
    if (posblk && wc == wr) {
        #pragma unroll
        for (int ar = 0; ar < 4; ++ar)
            #pragma unroll
            for (int reg = 0; reg < 4; ++reg)
                if (cq == quad * 4 + reg) {
                    int gr = rowbase + wr * 64 + ar * 16 + quad * 4 + reg;
                    pos_ws[gr] = acc[ar][ar][reg] * LN2F;
                }
    }

    // exp2 is the native op: one v_exp_f32 per element.
    #pragma unroll
    for (int ar = 0; ar < 4; ++ar)
        #pragma unroll
        for (int bc = 0; bc < 4; ++bc)
            #pragma unroll
            for (int reg = 0; reg < 4; ++reg)
                acc[ar][bc][reg] = fast_exp2(acc[ar][bc][reg]);
    if (diagblk && wr == wc) {
        #pragma unroll
        for (int ar = 0; ar < 4; ++ar)
            #pragma unroll
            for (int reg = 0; reg < 4; ++reg)
                if (cq == quad * 4 + reg) acc[ar][ar][reg] = 0.0f;
    }

    float* rsum_lds = sum_lds;            // [0..127]
    float* csum_lds = sum_lds + BM;       // [128..255]

    // Row sums: sum over 16 cols (bc in-register, cq via shuffle).
    #pragma unroll
    for (int ar = 0; ar < 4; ++ar) {
        float rs[4];
        #pragma unroll
        for (int reg = 0; reg < 4; ++reg) {
            float v = acc[ar][0][reg] + acc[ar][1][reg] + acc[ar][2][reg] + acc[ar][3][reg];
            v += __shfl_xor(v, 1); v += __shfl_xor(v, 2);
            v += __shfl_xor(v, 4); v += __shfl_xor(v, 8);
            rs[reg] = v;
        }
        if (cq == 0) {
            #pragma unroll
            for (int reg = 0; reg < 4; ++reg)
                atomicAdd(&rsum_lds[wr * 64 + ar * 16 + quad * 4 + reg], rs[reg]);
        }
    }

    // Col sums (symmetry): only for off-diagonal blocks.
    if (!diagblk) {
        #pragma unroll
        for (int bc = 0; bc < 4; ++bc) {
            float cs = 0.0f;
            #pragma unroll
            for (int ar = 0; ar < 4; ++ar)
                #pragma unroll
                for (int reg = 0; reg < 4; ++reg)
                    cs += acc[ar][bc][reg];
            cs += __shfl_xor(cs, 16); cs += __shfl_xor(cs, 32);
            if (quad == 0) atomicAdd(&csum_lds[wc * 64 + bc * 16 + cq], cs);
        }
    }

    __syncthreads();
    if (tid < BM) atomicAdd(&rowsum[rowbase + tid], rsum_lds[tid]);
    else if (!diagblk) atomicAdd(&rowsum[colbase + tid - BM], csum_lds[tid - BM]);
}

// Kernel 3: single block. mean_r( log(rowsum[r]) - pos[r & (BHALF-1)] ).
__global__ __launch_bounds__(256) void finalize_kernel(
    const float* __restrict__ rowsum, const float* __restrict__ pos_ws,
    float* __restrict__ out)
{
    __shared__ float red[4];
    float s = 0.0f;
    for (int r = threadIdx.x; r < N_TOT; r += 256)
        s += __logf(rowsum[r]) - pos_ws[r & (BHALF - 1)];
    #pragma unroll
    for (int off = 1; off < 64; off <<= 1) s += __shfl_xor(s, off);
    int wave = threadIdx.x >> 6, lane = threadIdx.x & 63;
    if (lane == 0) red[wave] = s;
    __syncthreads();
    if (threadIdx.x == 0)
        out[0] = (red[0] + red[1] + red[2] + red[3]) * (1.0f / N_TOT);
}

extern "C" void kernel_launch(void* const* d_in, const int* in_sizes, int n_in,
                              void* d_out, int out_size, void* d_ws, size_t ws_size,
                              hipStream_t stream) {
    const float* zis = (const float*)d_in[0];
    const float* zjs = (const float*)d_in[1];
    float* rowsum = (float*)d_ws;                                   // 32 KB
    float* pos_ws = rowsum + N_TOT;                                 // 16 KB
    unsigned short* zb = (unsigned short*)(pos_ws + BHALF);         // 8 MB, 16B-aligned
    float* out = (float*)d_out;

    normalize_kernel<<<N_TOT / 4, 256, 0, stream>>>(zis, zjs, zb, rowsum);
    ntxent_tri_kernel<<<NBLOCKS, 256, 0, stream>>>(zb, rowsum, pos_ws);
    finalize_kernel<<<1, 256, 0, stream>>>(rowsum, pos_ws, out);
}